// Round 6
// baseline (248.082 us; speedup 1.0000x reference)
//
#include <hip/hip_runtime.h>
#include <hip/hip_fp16.h>

constexpr int Tt = 384;   // timesteps
constexpr int Cc = 96;    // classes (blank = 95)
constexpr int Ll = 48;    // max label length
constexpr int Gg = 8;     // rows per group (= rescale period)
constexpr int NG = 24;    // groups per half (24*8 = 192)
constexpr int ES = 64;    // emission row stride (halves)

#define L2E 1.4426950408889634f
#define LN2 0.6931471805599453f
#define LNEG (-3.0e38f)

// ---- DPP helpers ----
template <int CTRL, int RM = 0xF>
__device__ __forceinline__ float dppf(float x) {
    return __int_as_float(
        __builtin_amdgcn_update_dpp(0, __float_as_int(x), CTRL, RM, 0xF, true));
}
template <int CTRL>
__device__ __forceinline__ int dppi(int x) {
    return __builtin_amdgcn_update_dpp(0, x, CTRL, 0xF, 0xF, true);
}
__device__ __forceinline__ float bcast63(float x) {
    return __int_as_float(__builtin_amdgcn_readlane(__float_as_int(x), 63));
}
// full-wave sum of non-negative values, result broadcast
__device__ __forceinline__ float wsum(float x) {
    x += dppf<0x111>(x);          // row_shr:1
    x += dppf<0x112>(x);          // row_shr:2
    x += dppf<0x114>(x);          // row_shr:4
    x += dppf<0x118>(x);          // row_shr:8
    x += dppf<0x142, 0xA>(x);     // row_bcast:15 -> rows 1,3
    x += dppf<0x143, 0xC>(x);     // row_bcast:31 -> rows 2,3
    return bcast63(x);
}
__device__ __forceinline__ float shup1(float x) { return dppf<0x138>(x); } // lane i <- i-1, 0 into lane 0
__device__ __forceinline__ float shdn1(float x) { return dppf<0x130>(x); } // lane i <- i+1, 0 into lane 63
__device__ __forceinline__ float exp2i(int d) {  // 2^d, clamped to fp32-normal range
    d = d < -126 ? -126 : (d > 126 ? 126 : d);
    return __int_as_float((d + 127) << 23);
}

// ============ Phase 1: emissions (parallel over B*T rows) ============
// em[b][t][lane]: lane<48 -> p(label_lane), lane>=48 -> p(blank), fp16.
__global__ __launch_bounds__(512) void emit_kernel(const int* __restrict__ labels,
                                                   const float* __restrict__ pred,
                                                   __half* __restrict__ em,
                                                   float* __restrict__ out) {
    const int b    = blockIdx.x;
    const int lane = threadIdx.x & 63;
    const int wv   = threadIdx.x >> 6;   // 0..7
    if (b == 0 && threadIdx.x == 0) *out = 0.0f;

    const float2* rp2  = (const float2*)(pred + (size_t)b * Tt * Cc);
    __half*       erow = em + (size_t)b * Tt * ES;

    int v = (lane < Ll) ? labels[(size_t)b * Ll + lane] : 0;
    int labv   = (v < 0) ? 0 : v;
    int idx_h  = labv >> 1;
    int bitsel = labv & 1;

    constexpr int U = 4;  // rows in flight per wave
    for (int base = wv; base < Tt; base += 8 * U) {
        float2 q[U];
#pragma unroll
        for (int u = 0; u < U; ++u) {
            int t = base + 8 * u;
            q[u] = (lane < 48) ? rp2[(size_t)t * 48 + lane] : make_float2(-1e4f, -1e4f);
        }
#pragma unroll
        for (int u = 0; u < U; ++u) {
            float ex = exp2f(q[u].x * L2E);
            float ey = exp2f(q[u].y * L2E);
            float s  = (lane < 48) ? (ex + ey) : 0.0f;
            float gb = __shfl(ey, 47, 64);      // class 95 (blank)
            float g0 = __shfl(ex, idx_h, 64);   // class 2*idx_h
            float g1 = __shfl(ey, idx_h, 64);   // class 2*idx_h+1
            s = wsum(s);
            float rZ = __builtin_amdgcn_rcpf(s);
            float pl = (bitsel ? g1 : g0) * rZ;
            float pb = gb * rZ;
            float val = (lane < 48) ? pl : pb;
            int t = base + 8 * u;
            erow[(size_t)t * ES + lane] = __float2half(val);
        }
    }
}

// ============ Phase 2: serial DP, linear space, per-lane exponent ============
template <bool FWD>
__device__ __forceinline__ void half_pass(const __half* __restrict__ erow, int lane,
                                          float allow2f, float& st_e, float& st_o, int& ls) {
    __half qr[4][Gg];                  // 4-group rolling prefetch
    float plC[Gg], pbC[Gg], plN[Gg], pbN[Gg];

    auto loadg = [&](__half* dst, int g) {
#pragma unroll
        for (int j = 0; j < Gg; ++j) {
            int k = g * Gg + j;
            int t = FWD ? k : (Tt - 1 - k);
            dst[j] = erow[(size_t)t * ES + lane];
        }
    };
    auto conv = [&](const __half* src, float* pl, float* pb) {
#pragma unroll
        for (int j = 0; j < Gg; ++j) {
            float vf = __half2float(src[j]);
            pl[j] = vf;
            pb[j] = __int_as_float(__builtin_amdgcn_readlane(__float_as_int(vf), 48));
        }
    };

    loadg(qr[0], 0); loadg(qr[1], 1); loadg(qr[2], 2); loadg(qr[3], 3);
    conv(qr[0], plC, pbC);

    float f   = 1.0f;        // 2^(ls_nbr - ls), constant within a group
    float a2f = allow2f;

#pragma unroll
    for (int g = 0; g < NG; ++g) {
        if (g + 1 < NG) conv(qr[(g + 1) & 3], plN, pbN);
        if (g + 4 < NG) loadg(qr[g & 3], g + 4);
#pragma unroll
        for (int j = 0; j < Gg; ++j) {
            if (FWD) {
                float sh = shup1(st_o);                      // alpha(2i-1)
                float t0 = st_e + st_o;
                float ne = fmaf(f, sh, st_e) * pbC[j];
                float no = fmaf(a2f, sh, t0) * plC[j];
                st_e = ne; st_o = no;
            } else {
                float en = shdn1(st_e);                      // beta(2i+2)
                float on = shdn1(st_o);                      // beta(2i+3)
                float ne = (st_e + st_o) * pbC[j];
                float no = fmaf(a2f, on, fmaf(f, en, st_o)) * plC[j];
                st_e = ne; st_o = no;
            }
        }
        // per-lane exact power-of-2 rescale
        float m = fmaxf(st_e, st_o);
        bool z  = (m == 0.0f);
        int eb  = (__float_as_int(m) >> 23) & 0xFF;
        eb = eb > 253 ? 253 : eb;
        float r = z ? 1.0f : __int_as_float((254 - eb) << 23);   // 2^(127-eb), exact
        st_e *= r; st_o *= r;
        ls += z ? 0 : (eb - 127);
        // exponent adoption for zero lanes (front moves <= 8 lanes/group)
#pragma unroll
        for (int it = 0; it < 8; ++it) {
            int lsn = FWD ? dppi<0x138>(ls) : dppi<0x130>(ls);
            ls = z ? lsn : ls;
        }
        int lsn2 = FWD ? dppi<0x138>(ls) : dppi<0x130>(ls);
        f   = exp2i(lsn2 - ls);
        a2f = allow2f * f;
        if (g + 1 < NG) {
#pragma unroll
            for (int j = 0; j < Gg; ++j) { plC[j] = plN[j]; pbC[j] = pbN[j]; }
        }
    }
}

__global__ __launch_bounds__(128) void ctc_fb2(const int* __restrict__ labels,
                                               const __half* __restrict__ em,
                                               float* __restrict__ out,
                                               float invB) {
    const int b    = blockIdx.x;
    const int lane = threadIdx.x & 63;
    const int wv   = threadIdx.x >> 6;
    const __half* erow = em + (size_t)b * Tt * ES;

    int v = (lane < Ll) ? labels[(size_t)b * Ll + lane] : -1;
    int present = (lane < Ll) && (v != -1);
    int labv = (v < 0) ? 0 : v;
    unsigned long long pm = __ballot(present);
    int len = __popcll(pm);

    int lab_p = __shfl(labv, (lane - 1) & 63, 64);
    int lab_n = __shfl(labv, (lane + 1) & 63, 64);

    __shared__ float sbe[64], sbo[64];
    __shared__ int   slsb[64];

    float Ae = 0.0f, Ao = 0.0f;
    int ls_f = 0;
    if (wv == 0) {
        // forward over t = 0..191, virtual pre-start at lane 0
        float allow2f = (lane >= 1 && labv != lab_p) ? 1.0f : 0.0f;
        float a_e = (lane == 0) ? 1.0f : 0.0f;
        float a_o = 0.0f;
        half_pass<true>(erow, lane, allow2f, a_e, a_o, ls_f);
        // transition half-step (no emission) to meet beta at t = 192
        float sh  = shup1(a_o);
        int   lsu = dppi<0x138>(ls_f);
        float fup = exp2i(lsu - ls_f);
        Ae = fmaf(fup, sh, a_e);
        Ao = fmaf(allow2f * fup, sh, a_e + a_o);
    } else {
        // backward over t = 383..192, virtual post-end at lane == len
        float allow2f = (labv != lab_n) ? 1.0f : 0.0f;
        float b_e = (lane == len) ? 1.0f : 0.0f;
        float b_o = 0.0f;
        int ls_b = 0;
        half_pass<false>(erow, lane, allow2f, b_e, b_o, ls_b);
        sbe[lane]  = b_e;
        sbo[lane]  = b_o;
        slsb[lane] = ls_b;
    }
    __syncthreads();

    if (wv == 0) {
        float be = sbe[lane], bo = sbo[lane];
        float base = (float)(ls_f + slsb[lane]);
        float l1 = (Ae > 0.0f && be > 0.0f) ? __log2f(Ae) + __log2f(be) + base : LNEG;
        float l2 = (Ao > 0.0f && bo > 0.0f) ? __log2f(Ao) + __log2f(bo) + base : LNEG;
        float mm = fmaxf(l1, l2);
#pragma unroll
        for (int off = 32; off >= 1; off >>= 1) mm = fmaxf(mm, __shfl_xor(mm, off, 64));
        float ss = exp2f(l1 - mm) + exp2f(l2 - mm);
#pragma unroll
        for (int off = 32; off >= 1; off >>= 1) ss += __shfl_xor(ss, off, 64);
        if (lane == 0) {
            float ll = (mm + __log2f(ss)) * LN2;
            atomicAdd(out, -ll * invB);
        }
    }
}

extern "C" void kernel_launch(void* const* d_in, const int* in_sizes, int n_in,
                              void* d_out, int out_size, void* d_ws, size_t ws_size,
                              hipStream_t stream) {
    const int*   labels = (const int*)d_in[0];
    const float* pred   = (const float*)d_in[1];
    float*       out    = (float*)d_out;
    __half*      em     = (__half*)d_ws;   // B*T*64 halves = 50.3 MB

    const int B = in_sizes[0] / Ll;  // 1024

    hipLaunchKernelGGL(emit_kernel, dim3(B), dim3(512), 0, stream, labels, pred, em, out);
    hipLaunchKernelGGL(ctc_fb2, dim3(B), dim3(128), 0, stream, labels, em, out, 1.0f / (float)B);
}

// Round 7
// 226.145 us; speedup vs baseline: 1.0970x; 1.0970x over previous
//
#include <hip/hip_runtime.h>

constexpr int Tt = 384;   // timesteps
constexpr int Cc = 96;    // classes (blank = 95)
constexpr int Ll = 48;    // max label length
constexpr int Gg = 8;     // rows per group (= rescale period)
constexpr int NG = 24;    // groups per half (24*8 = 192)

#define L2E 1.4426950408889634f
#define LN2 0.6931471805599453f
#define LNEG (-3.0e38f)

// ---- DPP helpers (VALU pipe) ----
template <int CTRL, int RM = 0xF>
__device__ __forceinline__ float dppf(float x) {
    return __int_as_float(
        __builtin_amdgcn_update_dpp(0, __float_as_int(x), CTRL, RM, 0xF, true));
}
template <int CTRL>
__device__ __forceinline__ int dppi(int x) {
    return __builtin_amdgcn_update_dpp(0, x, CTRL, 0xF, 0xF, true);
}
__device__ __forceinline__ float bcast63(float x) {
    return __int_as_float(__builtin_amdgcn_readlane(__float_as_int(x), 63));
}
// full-wave sum of non-negative values, result broadcast
__device__ __forceinline__ float wsum(float x) {
    x += dppf<0x111>(x);          // row_shr:1
    x += dppf<0x112>(x);          // row_shr:2
    x += dppf<0x114>(x);          // row_shr:4
    x += dppf<0x118>(x);          // row_shr:8
    x += dppf<0x142, 0xA>(x);     // row_bcast:15 -> rows 1,3
    x += dppf<0x143, 0xC>(x);     // row_bcast:31 -> rows 2,3
    return bcast63(x);
}
__device__ __forceinline__ float shup1(float x) { return dppf<0x138>(x); } // lane i <- i-1, 0 into lane 0
__device__ __forceinline__ float shdn1(float x) { return dppf<0x130>(x); } // lane i <- i+1, 0 into lane 63
__device__ __forceinline__ float exp2i(int d) {  // 2^d, clamped to fp32-normal range
    d = d < -126 ? -126 : (d > 126 ? 126 : d);
    return __int_as_float((d + 127) << 23);
}

// ---- producer: load one 8-row group of logits ----
template <bool FWD>
__device__ __forceinline__ void prod_load(const float2* __restrict__ rp2, float2* q,
                                          int g, int lane) {
#pragma unroll
    for (int j = 0; j < Gg; ++j) {
        int k = g * Gg + j;
        int t = FWD ? k : (Tt - 1 - k);
        q[j] = (lane < 48) ? rp2[(size_t)t * 48 + lane] : make_float2(-1e4f, -1e4f);
    }
}
// ---- producer: softmax + gather -> LDS row buffer ----
// dst[j*64 + lane]: lane<49 & >=50 -> p(label_lane) (junk-but-finite beyond states),
// lane 49 -> p(blank). All 64 lanes written (keeps LDS NaN-free for consumers).
__device__ __forceinline__ void prod_group(const float2* q, float* dst, int lane,
                                           int idx_h, int bitsel) {
#pragma unroll
    for (int j = 0; j < Gg; ++j) {
        float ex = exp2f(q[j].x * L2E);
        float ey = exp2f(q[j].y * L2E);
        float s  = (lane < 48) ? (ex + ey) : 0.0f;
        float gb = __shfl(ey, 47, 64);      // class 95 (blank)
        float g0 = __shfl(ex, idx_h, 64);   // class 2*idx_h
        float g1 = __shfl(ey, idx_h, 64);   // class 2*idx_h+1
        s = wsum(s);
        float rZ = __builtin_amdgcn_rcpf(s);
        float pl = (bitsel ? g1 : g0) * rZ;
        float pb = gb * rZ;
        dst[j * 64 + lane] = (lane == 49) ? pb : pl;
    }
}

// ---- consumer: one 8-step DP group, linear space, per-lane exponent ----
template <bool FWD>
__device__ __forceinline__ void dp_group(const float* __restrict__ pr, int lane,
                                         float allow2f, float& st_e, float& st_o,
                                         int& ls, float& f, float& a2f) {
    float plC[Gg], pbC[Gg];
#pragma unroll
    for (int j = 0; j < Gg; ++j) {
        plC[j] = pr[j * 64 + lane];
        pbC[j] = pr[j * 64 + 49];     // uniform address -> LDS broadcast
    }
#pragma unroll
    for (int j = 0; j < Gg; ++j) {
        if (FWD) {
            float sh = shup1(st_o);                      // alpha(2i-1), lane i-1 scale
            float t0 = st_e + st_o;
            float ne = fmaf(f, sh, st_e) * pbC[j];
            float no = fmaf(a2f, sh, t0) * plC[j];
            st_e = ne; st_o = no;
        } else {
            float en = shdn1(st_e);                      // beta(2i+2)
            float on = shdn1(st_o);                      // beta(2i+3)
            float ne = (st_e + st_o) * pbC[j];
            float no = fmaf(a2f, on, fmaf(f, en, st_o)) * plC[j];
            st_e = ne; st_o = no;
        }
    }
    // per-lane exact power-of-2 rescale
    float m = fmaxf(st_e, st_o);
    bool z  = (m == 0.0f);
    int eb  = (__float_as_int(m) >> 23) & 0xFF;
    eb = eb > 253 ? 253 : eb;
    float r = z ? 1.0f : __int_as_float((254 - eb) << 23);   // 2^(127-eb), exact
    st_e *= r; st_o *= r;
    ls += z ? 0 : (eb - 127);
    // exponent adoption for zero lanes (front moves <= 8 lanes/group)
#pragma unroll
    for (int it = 0; it < 8; ++it) {
        int lsn = FWD ? dppi<0x138>(ls) : dppi<0x130>(ls);
        ls = z ? lsn : ls;
    }
    int lsn2 = FWD ? dppi<0x138>(ls) : dppi<0x130>(ls);
    f   = exp2i(lsn2 - ls);
    a2f = allow2f * f;
}

__global__ __launch_bounds__(64) void zero_kernel(float* o) { *o = 0.0f; }

// 4 waves/block: wv0 = fwd DP, wv1 = bwd DP, wv2 = fwd producer, wv3 = bwd producer.
__global__ __launch_bounds__(256) void ctc_fb(const int* __restrict__ labels,
                                              const float* __restrict__ pred,
                                              float* __restrict__ out,
                                              float invB) {
    const int b    = blockIdx.x;
    const int lane = threadIdx.x & 63;
    const int wv   = threadIdx.x >> 6;
    const float2* rp2 = (const float2*)(pred + (size_t)b * Tt * Cc);

    __shared__ float plb[2][2][Gg][64];   // [dir][slot][row][lane], 8 KB
    __shared__ float sbe[64], sbo[64];
    __shared__ int   slsb[64];

    // lane i holds label i
    int v = (lane < Ll) ? labels[(size_t)b * Ll + lane] : -1;
    int present = (lane < Ll) && (v != -1);
    int labv = (v < 0) ? 0 : v;
    unsigned long long pm = __ballot(present);
    int len = __popcll(pm);
    int idx_h  = labv >> 1;
    int bitsel = labv & 1;
    int lab_p = __shfl(labv, (lane - 1) & 63, 64);
    int lab_n = __shfl(labv, (lane + 1) & 63, 64);

    float st_e = 0.0f, st_o = 0.0f, f = 1.0f, a2f = 0.0f, allow2f = 0.0f;
    int   ls = 0;
    float2 qA[Gg], qB[Gg];

    if (wv == 0) {            // fwd DP: virtual pre-start state at lane 0
        allow2f = (lane >= 1 && labv != lab_p) ? 1.0f : 0.0f;
        st_e = (lane == 0) ? 1.0f : 0.0f;
        a2f = allow2f;
    } else if (wv == 1) {     // bwd DP: virtual post-end state at lane == len
        allow2f = (labv != lab_n) ? 1.0f : 0.0f;
        st_e = (lane == len) ? 1.0f : 0.0f;
        a2f = allow2f;
    } else if (wv == 2) {
        prod_load<true>(rp2, qA, 0, lane);
        prod_load<true>(rp2, qB, 1, lane);
    } else {
        prod_load<false>(rp2, qA, 0, lane);
        prod_load<false>(rp2, qB, 1, lane);
    }

    for (int i = 0; i <= NG; ++i) {
        if (wv == 2 && i < NG) {
            if ((i & 1) == 0) {
                prod_group(qA, &plb[0][0][0][0], lane, idx_h, bitsel);
                if (i + 2 < NG) prod_load<true>(rp2, qA, i + 2, lane);
            } else {
                prod_group(qB, &plb[0][1][0][0], lane, idx_h, bitsel);
                if (i + 2 < NG) prod_load<true>(rp2, qB, i + 2, lane);
            }
        } else if (wv == 3 && i < NG) {
            if ((i & 1) == 0) {
                prod_group(qA, &plb[1][0][0][0], lane, idx_h, bitsel);
                if (i + 2 < NG) prod_load<false>(rp2, qA, i + 2, lane);
            } else {
                prod_group(qB, &plb[1][1][0][0], lane, idx_h, bitsel);
                if (i + 2 < NG) prod_load<false>(rp2, qB, i + 2, lane);
            }
        } else if (wv == 0 && i >= 1) {
            dp_group<true>(&plb[0][(i - 1) & 1][0][0], lane, allow2f, st_e, st_o, ls, f, a2f);
        } else if (wv == 1 && i >= 1) {
            dp_group<false>(&plb[1][(i - 1) & 1][0][0], lane, allow2f, st_e, st_o, ls, f, a2f);
        }
        __syncthreads();
    }

    if (wv == 1) {
        sbe[lane]  = st_e;
        sbo[lane]  = st_o;
        slsb[lane] = ls;
    }
    __syncthreads();

    if (wv == 0) {
        // transition half-step (no emission) to meet beta at t = 192
        float sh  = shup1(st_o);
        int   lsu = dppi<0x138>(ls);
        float fup = exp2i(lsu - ls);
        float Ae = fmaf(fup, sh, st_e);
        float Ao = fmaf(allow2f * fup, sh, st_e + st_o);
        // combine in log2 domain with integer exponents restored
        float be = sbe[lane], bo = sbo[lane];
        float base = (float)(ls + slsb[lane]);
        float l1 = (Ae > 0.0f && be > 0.0f) ? __log2f(Ae) + __log2f(be) + base : LNEG;
        float l2 = (Ao > 0.0f && bo > 0.0f) ? __log2f(Ao) + __log2f(bo) + base : LNEG;
        float mm = fmaxf(l1, l2);
#pragma unroll
        for (int off = 32; off >= 1; off >>= 1) mm = fmaxf(mm, __shfl_xor(mm, off, 64));
        float ss = exp2f(l1 - mm) + exp2f(l2 - mm);
#pragma unroll
        for (int off = 32; off >= 1; off >>= 1) ss += __shfl_xor(ss, off, 64);
        if (lane == 0) {
            float ll = (mm + __log2f(ss)) * LN2;
            atomicAdd(out, -ll * invB);
        }
    }
}

extern "C" void kernel_launch(void* const* d_in, const int* in_sizes, int n_in,
                              void* d_out, int out_size, void* d_ws, size_t ws_size,
                              hipStream_t stream) {
    const int*   labels = (const int*)d_in[0];
    const float* pred   = (const float*)d_in[1];
    float*       out    = (float*)d_out;

    const int B = in_sizes[0] / Ll;  // 1024

    hipLaunchKernelGGL(zero_kernel, dim3(1), dim3(64), 0, stream, out);
    hipLaunchKernelGGL(ctc_fb, dim3(B), dim3(256), 0, stream,
                       labels, pred, out, 1.0f / (float)B);
}